// Round 1
// baseline (150.177 us; speedup 1.0000x reference)
//
#include <hip/hip_runtime.h>
#include <math.h>

#define NV 12
#define NC 256
#define NBINS 5
#define EPS 1e-6f

// One wave (64 lanes) per row n. Lane owns 4 channels (float4).
// No LDS, no barriers: butterfly shuffle reduction + redundant scalar math.
__global__ __launch_bounds__(256) void gvcnn_kernel(
    const float* __restrict__ RPs,
    const float* __restrict__ w,
    const float* __restrict__ b,
    float* __restrict__ out)
{
    const int wave = threadIdx.x >> 6;
    const int lane = threadIdx.x & 63;
    const int n = (blockIdx.x << 2) + wave;   // grid = 2048, 4 waves/block -> n in [0, 8192)

    const float4* rp = (const float4*)(RPs + (size_t)n * NV * NC) + lane; // 64 float4 per view-row
    float4 x[NV];
#pragma unroll
    for (int v = 0; v < NV; ++v) x[v] = rp[v * 64];

    const float4 w4 = ((const float4*)w)[lane];
    const float bv = b[0];

    // per-lane partial dot products
    float p[NV];
#pragma unroll
    for (int v = 0; v < NV; ++v)
        p[v] = x[v].x * w4.x + x[v].y * w4.y + x[v].z * w4.z + x[v].w * w4.w;

    // 64-lane butterfly reduce; all lanes end with the full sum
#pragma unroll
    for (int m = 1; m < 64; m <<= 1) {
#pragma unroll
        for (int v = 0; v < NV; ++v)
            p[v] += __shfl_xor(p[v], m, 64);
    }

    // scores and bin ids (redundant on all lanes)
    float s[NV];
    int gid[NV];
#pragma unroll
    for (int v = 0; v < NV; ++v) {
        float a = fabsf(p[v] + bv) + EPS;
        s[v] = a / (1.0f + a);                  // sigmoid(log(a)) == a/(1+a)
        int t = (int)(s[v] * 10.0f);            // s in (0,1) -> floor
        if (t > 9) t = 9;
        gid[v] = t >> 1;                        // 0..4
    }

    // group sizes (static indexing only -> stays in registers)
    float gsize[NBINS];
#pragma unroll
    for (int g = 0; g < NBINS; ++g) {
        float c = 0.0f;
#pragma unroll
        for (int v = 0; v < NV; ++v) c += (gid[v] == g) ? 1.0f : 0.0f;
        gsize[g] = c;
    }

    // group scores: sum_v ceil(score_v * gsize[g]) over members, / (gsize+eps)
    float gscore[NBINS];
    float gss = 0.0f;
#pragma unroll
    for (int g = 0; g < NBINS; ++g) {
        float c = 0.0f;
#pragma unroll
        for (int v = 0; v < NV; ++v)
            c += (gid[v] == g) ? ceilf(s[v] * gsize[g]) : 0.0f;
        gscore[g] = c / (gsize[g] + EPS);
        gss += gscore[g];
    }

    // per-group output coefficient
    float coef[NBINS];
#pragma unroll
    for (int g = 0; g < NBINS; ++g)
        coef[g] = gscore[g] / ((gsize[g] + EPS) * (gss + EPS));

    // out[c] = sum_v x_v[c] * coef[gid_v]
    float4 o = {0.0f, 0.0f, 0.0f, 0.0f};
#pragma unroll
    for (int v = 0; v < NV; ++v) {
        float cv = coef[0];
#pragma unroll
        for (int g = 1; g < NBINS; ++g) cv = (gid[v] == g) ? coef[g] : cv;
        o.x += x[v].x * cv;
        o.y += x[v].y * cv;
        o.z += x[v].z * cv;
        o.w += x[v].w * cv;
    }
    ((float4*)(out + (size_t)n * NC))[lane] = o;
}

extern "C" void kernel_launch(void* const* d_in, const int* in_sizes, int n_in,
                              void* d_out, int out_size, void* d_ws, size_t ws_size,
                              hipStream_t stream) {
    const float* RPs = (const float*)d_in[0];  // [8192, 12, 256] fp32
    const float* w   = (const float*)d_in[1];  // [256] fp32
    const float* b   = (const float*)d_in[2];  // [1] fp32
    float* out = (float*)d_out;                // [8192, 256] fp32

    gvcnn_kernel<<<2048, 256, 0, stream>>>(RPs, w, b, out);
}

// Round 3
// 145.380 us; speedup vs baseline: 1.0330x; 1.0330x over previous
//
#include <hip/hip_runtime.h>
#include <math.h>

#define NV 12
#define NC 256
#define NBINS 5
#define EPS 1e-6f

// Native vector type (clang ext_vector) — required by __builtin_nontemporal_*
typedef float f4 __attribute__((ext_vector_type(4)));

// One wave (64 lanes) per row n. Lane owns 4 channels (f4).
// No LDS, no barriers: butterfly shuffle reduction + redundant scalar math.
// RPs is read exactly once and out written exactly once per launch ->
// non-temporal hints to skip cache allocation.
__global__ __launch_bounds__(256, 4) void gvcnn_kernel(
    const float* __restrict__ RPs,
    const float* __restrict__ w,
    const float* __restrict__ b,
    float* __restrict__ out)
{
    const int wave = threadIdx.x >> 6;
    const int lane = threadIdx.x & 63;
    const int n = (blockIdx.x << 2) + wave;   // grid = 2048, 4 waves/block -> n in [0, 8192)

    // uniform/small loads first
    const f4 w4 = ((const f4*)w)[lane];
    const float bv = b[0];

    const f4* rp = (const f4*)(RPs + (size_t)n * NV * NC) + lane; // 64 f4 per view-row
    f4 x[NV];
#pragma unroll
    for (int v = 0; v < NV; ++v) x[v] = __builtin_nontemporal_load(rp + v * 64);

    // per-lane partial dot products
    float p[NV];
#pragma unroll
    for (int v = 0; v < NV; ++v)
        p[v] = fmaf(x[v].x, w4.x, fmaf(x[v].y, w4.y, fmaf(x[v].z, w4.z, x[v].w * w4.w)));

    // 64-lane butterfly reduce; all lanes end with the full sum
#pragma unroll
    for (int m = 1; m < 64; m <<= 1) {
#pragma unroll
        for (int v = 0; v < NV; ++v)
            p[v] += __shfl_xor(p[v], m, 64);
    }

    // scores and bin ids (redundant on all lanes)
    float s[NV];
    int gid[NV];
#pragma unroll
    for (int v = 0; v < NV; ++v) {
        float a = fabsf(p[v] + bv) + EPS;
        s[v] = a / (1.0f + a);                  // sigmoid(log(a)) == a/(1+a)
        int t = (int)(s[v] * 10.0f);            // s in (0,1) -> floor
        if (t > 9) t = 9;
        gid[v] = t >> 1;                        // 0..4
    }

    // group sizes (static indexing only -> stays in registers)
    float gsize[NBINS];
#pragma unroll
    for (int g = 0; g < NBINS; ++g) {
        float c = 0.0f;
#pragma unroll
        for (int v = 0; v < NV; ++v) c += (gid[v] == g) ? 1.0f : 0.0f;
        gsize[g] = c;
    }

    // group scores: sum_v ceil(score_v * gsize[g]) over members, / (gsize+eps)
    float gscore[NBINS];
    float gss = 0.0f;
#pragma unroll
    for (int g = 0; g < NBINS; ++g) {
        float c = 0.0f;
#pragma unroll
        for (int v = 0; v < NV; ++v)
            c += (gid[v] == g) ? ceilf(s[v] * gsize[g]) : 0.0f;
        gscore[g] = c / (gsize[g] + EPS);
        gss += gscore[g];
    }

    // per-group output coefficient
    float coef[NBINS];
#pragma unroll
    for (int g = 0; g < NBINS; ++g)
        coef[g] = gscore[g] / ((gsize[g] + EPS) * (gss + EPS));

    // out[c] = sum_v x_v[c] * coef[gid_v]
    f4 o = {0.0f, 0.0f, 0.0f, 0.0f};
#pragma unroll
    for (int v = 0; v < NV; ++v) {
        float cv = coef[0];
#pragma unroll
        for (int g = 1; g < NBINS; ++g) cv = (gid[v] == g) ? coef[g] : cv;
        o.x = fmaf(x[v].x, cv, o.x);
        o.y = fmaf(x[v].y, cv, o.y);
        o.z = fmaf(x[v].z, cv, o.z);
        o.w = fmaf(x[v].w, cv, o.w);
    }
    __builtin_nontemporal_store(o, (f4*)(out + (size_t)n * NC) + lane);
}

extern "C" void kernel_launch(void* const* d_in, const int* in_sizes, int n_in,
                              void* d_out, int out_size, void* d_ws, size_t ws_size,
                              hipStream_t stream) {
    const float* RPs = (const float*)d_in[0];  // [8192, 12, 256] fp32
    const float* w   = (const float*)d_in[1];  // [256] fp32
    const float* b   = (const float*)d_in[2];  // [1] fp32
    float* out = (float*)d_out;                // [8192, 256] fp32

    gvcnn_kernel<<<2048, 256, 0, stream>>>(RPs, w, b, out);
}